// Round 1
// 422.931 us; speedup vs baseline: 1.0101x; 1.0101x over previous
//
#include <hip/hip_runtime.h>
#include <cstdint>

#define DEVINL __device__ __forceinline__

typedef uint16_t u16;
typedef uint32_t u32;
typedef uint64_t u64;
typedef __attribute__((ext_vector_type(8))) short short8;
typedef __attribute__((ext_vector_type(4))) float floatx4;
typedef __attribute__((ext_vector_type(4))) u32 u32x4;
typedef const __attribute__((address_space(1))) void* gas_ptr;
typedef __attribute__((address_space(3))) void* las_ptr;

DEVINL u16 f2bf(float f) {
  u32 u = __float_as_uint(f);
  u32 r = u + 0x7FFFu + ((u >> 16) & 1u);   // RNE
  return (u16)(r >> 16);
}
DEVINL float bf2f(u16 b) { return __uint_as_float((u32)b << 16); }
DEVINL float bf_lo(u32 u) { return __uint_as_float(u << 16); }
DEVINL float bf_hi(u32 u) { return __uint_as_float(u & 0xFFFF0000u); }

// ---------- row_start[n] = lower_bound(dst, n) over sorted dst ----------
__global__ void rowstart_kernel(const int* __restrict__ dst, int* __restrict__ rs,
                                int N, int E) {
  int n = blockIdx.x * blockDim.x + threadIdx.x;
  if (n > N) return;
  int lo = 0, hi = E;
  while (lo < hi) { int mid = (lo + hi) >> 1; if (dst[mid] < n) lo = mid + 1; else hi = mid; }
  rs[n] = lo;
}

__global__ void zero_kernel(float* __restrict__ p, int n) {
  int i = blockIdx.x * blockDim.x + threadIdx.x;
  if (i < n) p[i] = 0.f;
}

// ---------- f32 -> 2-plane split-bf16: A'=[hi|lo], B'=[hi|hi], row len 2K ----------
// A-side: exact split (hi+lo = a to f32 precision). B-side: weights bf16-quantized.
template<bool IsA>
__global__ __launch_bounds__(256)
void split_kernel(const float* __restrict__ in, u16* __restrict__ out, int MK, int K) {
  int idx = blockIdx.x * blockDim.x + threadIdx.x;
  if (idx >= MK) return;
  int m = idx / K, k = idx - m * K;
  float a = in[idx];
  u16 h = f2bf(a);
  size_t base = (size_t)m * 2 * K;
  if (IsA) {
    u16 lo = f2bf(a - bf2f(h));
    out[base + k] = h;  out[base + K + k] = lo;
  } else {
    out[base + k] = h;  out[base + K + k] = h;
  }
}

// ---------- GEMM: C[M,Nout] = A'[M,K'] * B'[Nout,K']^T  (split-bf16 in) ----------
// BM=128, BK=32, 256 threads (4 waves); wave w owns rows [32w,32w+32).
// OUTM: 1 = bf16 store, 2 = f32 atomicAdd (split-K: blockIdx.x indexes K-chunk).
template<int BN, int OUTM>
__global__ __launch_bounds__(256)
void gemm_bt_kernel(const u16* __restrict__ A, const u16* __restrict__ B,
                    float* __restrict__ Cf, u16* __restrict__ Cb,
                    int M, int Nout, int K, int kLen)
{
  constexpr int BM = 128, BK = 32, CF = BN / 16;
  constexpr int BCALLS = (BN * BK) / 512;          // 8 for BN=128, 2 for BN=32
  __shared__ __align__(16) u16 As[BM * BK];
  __shared__ __align__(16) u16 Bs[BN * BK];
  const int tid  = threadIdx.x;
  const int wave = tid >> 6;
  const int lane = tid & 63;
  const int quad = lane >> 4;
  const int l16  = lane & 15;
  const int rowBase = blockIdx.y * BM;
  const int colBase = (OUTM == 2) ? 0 : blockIdx.x * BN;
  const int kStart  = (OUTM == 2) ? blockIdx.x * kLen : 0;

  floatx4 acc[2][CF];
  #pragma unroll
  for (int r = 0; r < 2; ++r)
    #pragma unroll
    for (int c = 0; c < CF; ++c)
      acc[r][c] = (floatx4){0.f, 0.f, 0.f, 0.f};

  // A staging: 8 wave-calls; wave w does calls {w, w+4}.
  int aRow[2], aCol[2];
  #pragma unroll
  for (int i = 0; i < 2; ++i) {
    int call = wave + 4 * i;
    int flat = call * 512 + lane * 8;              // elem idx in 128x32 tile
    int r = flat >> 5;
    aCol[i] = flat & 31;
    int gr = rowBase + r;
    if (gr >= M) gr = M - 1;                       // clamp: safe load, store guarded
    aRow[i] = gr;
  }
  // B staging: BCALLS wave-calls; wave w does {w, w+4} below BCALLS.
  int bRow[2] = {0, 0}, bCol[2] = {0, 0};
  #pragma unroll
  for (int i = 0; i < 2; ++i) {
    int call = wave + 4 * i;
    if (call < BCALLS) {
      int flat = call * 512 + lane * 8;
      bRow[i] = colBase + (flat >> 5);
      bCol[i] = flat & 31;
    }
  }

  for (int k0 = kStart; k0 < kStart + kLen; k0 += BK) {
    __syncthreads();
    #pragma unroll
    for (int i = 0; i < 2; ++i) {
      int call = wave + 4 * i;
      const u16* gp = A + (size_t)aRow[i] * K + (k0 + aCol[i]);
      __builtin_amdgcn_global_load_lds((gas_ptr)gp,
          (las_ptr)(As + call * 512), 16, 0, 0);
    }
    #pragma unroll
    for (int i = 0; i < 2; ++i) {
      int call = wave + 4 * i;
      if (call < BCALLS) {
        const u16* gp = B + (size_t)bRow[i] * K + (k0 + bCol[i]);
        __builtin_amdgcn_global_load_lds((gas_ptr)gp,
            (las_ptr)(Bs + call * 512), 16, 0, 0);
      }
    }
    __syncthreads();
    short8 a0 = *(const short8*)(As + (32 * wave + l16) * BK + quad * 8);
    short8 a1 = *(const short8*)(As + (32 * wave + 16 + l16) * BK + quad * 8);
    #pragma unroll
    for (int c = 0; c < CF; ++c) {
      short8 b = *(const short8*)(Bs + (16 * c + l16) * BK + quad * 8);
      acc[0][c] = __builtin_amdgcn_mfma_f32_16x16x32_bf16(a0, b, acc[0][c], 0, 0, 0);
      acc[1][c] = __builtin_amdgcn_mfma_f32_16x16x32_bf16(a1, b, acc[1][c], 0, 0, 0);
    }
  }

  // C/D layout: col = lane&15, row = quad*4 + reg (verified m89/m91)
  #pragma unroll
  for (int rt = 0; rt < 2; ++rt)
    #pragma unroll
    for (int c = 0; c < CF; ++c)
      #pragma unroll
      for (int i = 0; i < 4; ++i) {
        int gr = rowBase + 32 * wave + 16 * rt + quad * 4 + i;
        if (gr < M) {
          int gc = colBase + 16 * c + l16;
          if (OUTM == 1) Cb[(size_t)gr * Nout + gc] = f2bf(acc[rt][c][i]);
          else           atomicAdd(Cf + (size_t)gr * Nout + gc, acc[rt][c][i]);
        }
      }
}

// ---------- el/er from bf16 z (H=8, F=64) ----------
__global__ __launch_bounds__(256)
void elr_bf16_kernel(const u16* __restrict__ z, const float* __restrict__ al,
                     const float* __restrict__ ar, float* __restrict__ el,
                     float* __restrict__ er, int N)
{
  int t = blockIdx.x * blockDim.x + threadIdx.x;
  if (t >= N * 8) return;
  int h = t & 7;
  const u32x4* zp = (const u32x4*)(z + (size_t)t * 64);
  const float* alp = al + h * 64;
  const float* arp = ar + h * 64;
  float sl = 0.f, sr = 0.f;
  #pragma unroll
  for (int i = 0; i < 8; ++i) {
    u32x4 zz = zp[i];
    #pragma unroll
    for (int j = 0; j < 4; ++j) {
      float z0 = bf_lo(zz[j]), z1 = bf_hi(zz[j]);
      int f = i * 8 + 2 * j;
      sl += z0 * alp[f] + z1 * alp[f + 1];
      sr += z0 * arp[f] + z1 * arp[f + 1];
    }
  }
  el[t] = sl;
  er[t] = sr;
}

// ---------- f32 elr (layer 3, H=1, F=32) ----------
template<int H, int F>
__global__ __launch_bounds__(256)
void elr_kernel(const float* __restrict__ z, const float* __restrict__ al,
                const float* __restrict__ ar, float* __restrict__ el,
                float* __restrict__ er, int N)
{
  int t = blockIdx.x * blockDim.x + threadIdx.x;
  if (t >= N * H) return;
  int h = t % H;
  const float4* zp  = (const float4*)(z + (size_t)t * F);
  const float4* alp = (const float4*)(al + h * F);
  const float4* arp = (const float4*)(ar + h * F);
  float sl = 0.f, sr = 0.f;
  #pragma unroll
  for (int i = 0; i < F / 4; ++i) {
    float4 zz = zp[i], aa = alp[i], rr = arp[i];
    sl += zz.x * aa.x + zz.y * aa.y + zz.z * aa.z + zz.w * aa.w;
    sr += zz.x * rr.x + zz.y * rr.y + zz.z * rr.z + zz.w * rr.w;
  }
  el[t] = sl;
  er[t] = sr;
}

// ---------- layers 1/2 aggregate: bf16 z gather, 1 wave/node, 8 cols/thread ----------
// out = sum_e exp(v_e) z[src_e] / sum_e exp(v_e)  (shift-invariant softmax, no max pass)
// Epilogue writes next layer's A' = [hi|lo] (row len 1024).
// BRANCHLESS chunk of 8: clamp index (src[min(k,e-1)]) + mask weight to 0 for k>=e.
// All 8 row-gathers issue from one basic block -> 8 loads in flight per wave
// (the guarded version serialized one ~1KB gather per edge at full latency).
// Adding 0.f to den/acc is exact -> numerics identical to guarded version.
__global__ __launch_bounds__(64)
void agg_bf16_kernel(const u16* __restrict__ z, const float* __restrict__ el,
                     const float* __restrict__ er, const int* __restrict__ src,
                     const int* __restrict__ rs, u16* __restrict__ a2out)
{
  const int n = blockIdx.x, tid = threadIdx.x;
  const int s = rs[n], e = rs[n + 1];
  const int c0 = tid * 8;                          // 8 bf16 cols = 16 B/lane
  const int h = tid >> 3;                          // c0 / 64
  const float er_h = er[(size_t)n * 8 + h];

  float acc[8];
  #pragma unroll
  for (int j = 0; j < 8; ++j) acc[j] = 0.f;
  float den = 0.f;

  for (int k0 = s; k0 < e; k0 += 8) {
    int si[8];                                     // wave-uniform -> SGPRs
    #pragma unroll
    for (int kk = 0; kk < 8; ++kk) {
      int k = k0 + kk;
      si[kk] = src[k < e ? k : e - 1];             // clamped: safe dup load
    }
    float vv[8];
    #pragma unroll
    for (int kk = 0; kk < 8; ++kk)
      vv[kk] = el[(size_t)si[kk] * 8 + h];         // 32B/edge broadcast-ish
    u32x4 zz[8];
    #pragma unroll
    for (int kk = 0; kk < 8; ++kk)
      zz[kk] = *(const u32x4*)(z + (size_t)si[kk] * 512 + c0);  // 1KB/wave coalesced
    #pragma unroll
    for (int kk = 0; kk < 8; ++kk) {
      float v = vv[kk] + er_h;
      v = (v > 0.f) ? v : 0.2f * v;                // leaky_relu 0.2
      float wgt = (k0 + kk < e) ? __expf(v) : 0.f; // mask pad edges exactly
      den += wgt;
      #pragma unroll
      for (int j = 0; j < 4; ++j) {
        acc[2 * j]     += wgt * bf_lo(zz[kk][j]);
        acc[2 * j + 1] += wgt * bf_hi(zz[kk][j]);
      }
    }
  }

  const float r = (e > s) ? (1.f / den) : 0.f;     // deg==0 -> zeros (elu(0)=0)
  u32x4 hp, lp;
  #pragma unroll
  for (int j = 0; j < 4; ++j) {
    float o0 = acc[2 * j] * r, o1 = acc[2 * j + 1] * r;
    o0 = (o0 > 0.f) ? o0 : (__expf(o0) - 1.f);     // elu
    o1 = (o1 > 0.f) ? o1 : (__expf(o1) - 1.f);
    u16 h0 = f2bf(o0), h1 = f2bf(o1);
    u16 l0 = f2bf(o0 - bf2f(h0)), l1 = f2bf(o1 - bf2f(h1));
    hp[j] = ((u32)h1 << 16) | h0;
    lp[j] = ((u32)l1 << 16) | l0;
  }
  u16* row = a2out + (size_t)n * 1024;             // A' = [hi|lo]
  *(u32x4*)(row + c0) = hp;
  *(u32x4*)(row + 512 + c0) = lp;
}

// ---------- layer 3 aggregate: f32 z3 (3.2 MB, L2-resident), 32 cols ----------
// Same branchless restructure; lanes 32-63 duplicate lanes 0-31's loads
// (same cache lines, store guarded).
__global__ __launch_bounds__(64)
void agg3_kernel(const float* __restrict__ z, const float* __restrict__ el,
                 const float* __restrict__ er, const int* __restrict__ src,
                 const int* __restrict__ rs, float* __restrict__ out)
{
  const int n = blockIdx.x, tid = threadIdx.x;
  const int s = rs[n], e = rs[n + 1];
  const int col = tid & 31;
  const float er_n = er[n];
  float acc = 0.f, den = 0.f;

  for (int k0 = s; k0 < e; k0 += 8) {
    int si[8];
    #pragma unroll
    for (int kk = 0; kk < 8; ++kk) {
      int k = k0 + kk;
      si[kk] = src[k < e ? k : e - 1];
    }
    float vv[8], zv[8];
    #pragma unroll
    for (int kk = 0; kk < 8; ++kk)
      vv[kk] = el[si[kk]];
    #pragma unroll
    for (int kk = 0; kk < 8; ++kk)
      zv[kk] = z[(size_t)si[kk] * 32 + col];
    #pragma unroll
    for (int kk = 0; kk < 8; ++kk) {
      float v = vv[kk] + er_n;
      v = (v > 0.f) ? v : 0.2f * v;
      float wgt = (k0 + kk < e) ? __expf(v) : 0.f;
      den += wgt;
      acc += wgt * zv[kk];
    }
  }
  if (tid < 32) out[(size_t)n * 32 + col] = (e > s) ? (acc / den) : 0.f;
}

extern "C" void kernel_launch(void* const* d_in, const int* in_sizes, int n_in,
                              void* d_out, int out_size, void* d_ws, size_t ws_size,
                              hipStream_t stream)
{
  constexpr int N = 25000, E = 400000, K1 = 256, HF = 512, CLS = 32;
  const float* h   = (const float*)d_in[0];
  const int*   src = (const int*)d_in[1];
  const int*   dst = (const int*)d_in[2];
  const float* W1  = (const float*)d_in[3];
  const float* al1 = (const float*)d_in[4];
  const float* ar1 = (const float*)d_in[5];
  const float* W2  = (const float*)d_in[6];
  const float* al2 = (const float*)d_in[7];
  const float* ar2 = (const float*)d_in[8];
  const float* W3  = (const float*)d_in[9];
  const float* al3 = (const float*)d_in[10];
  const float* ar3 = (const float*)d_in[11];
  float* out = (float*)d_out;

  char* w = (char*)d_ws;
  auto take = [&](size_t bytes) {
    char* p = w;
    w += (bytes + 255) & ~(size_t)255;
    return p;
  };
  int*   rs = (int*)  take((size_t)(N + 1) * sizeof(int));
  float* el = (float*)take((size_t)N * 8 * sizeof(float));
  float* er = (float*)take((size_t)N * 8 * sizeof(float));
  float* z3 = (float*)take((size_t)N * CLS * sizeof(float));         // 3.2 MB
  u16*   zb = (u16*)  take((size_t)N * HF * sizeof(u16));            // 25.6 MB
  u16*   A2 = (u16*)  take((size_t)N * 2 * HF * sizeof(u16));        // 51.2 MB
  u16*   B2 = (u16*)  take((size_t)HF * 2 * HF * sizeof(u16));       // 1.05 MB

  rowstart_kernel<<<dim3((N + 1 + 255) / 256), 256, 0, stream>>>(dst, rs, N, E);

  const dim3 gemmGrid(HF / 128, (N + 127) / 128);   // 4 x 196

  // ---- Layer 1: K'=512 ----
  split_kernel<true ><<<dim3((N * K1 + 255) / 256), 256, 0, stream>>>(h,  A2, N * K1, K1);
  split_kernel<false><<<dim3((HF * K1 + 255) / 256), 256, 0, stream>>>(W1, B2, HF * K1, K1);
  gemm_bt_kernel<128, 1><<<gemmGrid, 256, 0, stream>>>(A2, B2, nullptr, zb, N, HF, 2 * K1, 2 * K1);
  elr_bf16_kernel<<<dim3((N * 8 + 255) / 256), 256, 0, stream>>>(zb, al1, ar1, el, er, N);
  agg_bf16_kernel<<<dim3(N), 64, 0, stream>>>(zb, el, er, src, rs, A2);

  // ---- Layer 2: K'=1024 ----
  split_kernel<false><<<dim3((HF * HF + 255) / 256), 256, 0, stream>>>(W2, B2, HF * HF, HF);
  gemm_bt_kernel<128, 1><<<gemmGrid, 256, 0, stream>>>(A2, B2, nullptr, zb, N, HF, 2 * HF, 2 * HF);
  elr_bf16_kernel<<<dim3((N * 8 + 255) / 256), 256, 0, stream>>>(zb, al2, ar2, el, er, N);
  agg_bf16_kernel<<<dim3(N), 64, 0, stream>>>(zb, el, er, src, rs, A2);

  // ---- Layer 3: K'=1024, Nout=32, split-K=4 + atomicAdd ----
  split_kernel<false><<<dim3((CLS * HF + 255) / 256), 256, 0, stream>>>(W3, B2, CLS * HF, HF);
  zero_kernel<<<dim3((N * CLS + 255) / 256), 256, 0, stream>>>(z3, N * CLS);
  gemm_bt_kernel<32, 2><<<dim3(4, (N + 127) / 128), 256, 0, stream>>>(A2, B2, z3, nullptr, N, CLS, 2 * HF, (2 * HF) / 4);
  elr_kernel<1, 32><<<dim3((N + 255) / 256), 256, 0, stream>>>(z3, al3, ar3, el, er, N);
  agg3_kernel<<<dim3(N), 64, 0, stream>>>(z3, el, er, src, rs, out);
}

// Round 2
// 402.863 us; speedup vs baseline: 1.0605x; 1.0498x over previous
//
#include <hip/hip_runtime.h>
#include <cstdint>

#define DEVINL __device__ __forceinline__

typedef uint16_t u16;
typedef uint32_t u32;
typedef uint64_t u64;
typedef __attribute__((ext_vector_type(8))) short short8;
typedef __attribute__((ext_vector_type(4))) float floatx4;
typedef __attribute__((ext_vector_type(4))) u32 u32x4;
typedef const __attribute__((address_space(1))) void* gas_ptr;
typedef __attribute__((address_space(3))) void* las_ptr;

DEVINL u16 f2bf(float f) {
  u32 u = __float_as_uint(f);
  u32 r = u + 0x7FFFu + ((u >> 16) & 1u);   // RNE
  return (u16)(r >> 16);
}
DEVINL float bf2f(u16 b) { return __uint_as_float((u32)b << 16); }
DEVINL float bf_lo(u32 u) { return __uint_as_float(u << 16); }
DEVINL float bf_hi(u32 u) { return __uint_as_float(u & 0xFFFF0000u); }

// ---------- row_start[n] = lower_bound(dst, n) over sorted dst ----------
__global__ void rowstart_kernel(const int* __restrict__ dst, int* __restrict__ rs,
                                int N, int E) {
  int n = blockIdx.x * blockDim.x + threadIdx.x;
  if (n > N) return;
  int lo = 0, hi = E;
  while (lo < hi) { int mid = (lo + hi) >> 1; if (dst[mid] < n) lo = mid + 1; else hi = mid; }
  rs[n] = lo;
}

// zero z3 + el + er in one launch (layer-3 atomic targets)
__global__ void zero3_kernel(float* __restrict__ z3, float* __restrict__ el,
                             float* __restrict__ er, int nz, int ne) {
  int i = blockIdx.x * blockDim.x + threadIdx.x;
  if (i < nz) { z3[i] = 0.f; return; }
  int j = i - nz;
  if (j < ne) { el[j] = 0.f; return; }
  j -= ne;
  if (j < ne) er[j] = 0.f;
}

// ---------- f32 -> 2-plane split-bf16: A'=[hi|lo], B'=[hi|hi], row len 2K ----------
// A-side: exact split (hi+lo = a to f32 precision). B-side: weights bf16-quantized.
template<bool IsA>
__global__ __launch_bounds__(256)
void split_kernel(const float* __restrict__ in, u16* __restrict__ out, int MK, int K) {
  int idx = blockIdx.x * blockDim.x + threadIdx.x;
  if (idx >= MK) return;
  int m = idx / K, k = idx - m * K;
  float a = in[idx];
  u16 h = f2bf(a);
  size_t base = (size_t)m * 2 * K;
  if (IsA) {
    u16 lo = f2bf(a - bf2f(h));
    out[base + k] = h;  out[base + K + k] = lo;
  } else {
    out[base + k] = h;  out[base + K + k] = h;
  }
}

// ---------- GEMM: C[M,Nout] = A'[M,K'] * B'[Nout,K']^T  (split-bf16 in) ----------
// BM=128, BK=32, 256 threads (4 waves); wave w owns rows [32w,32w+32).
// OUTM: 1 = bf16 store + el/er store epilogue (cols of a block cover whole heads),
//       2 = f32 atomicAdd (split-K) + el/er atomicAdd epilogue (linear in partials).
template<int BN, int OUTM>
__global__ __launch_bounds__(256)
void gemm_bt_kernel(const u16* __restrict__ A, const u16* __restrict__ B,
                    float* __restrict__ Cf, u16* __restrict__ Cb,
                    const float* __restrict__ al, const float* __restrict__ ar,
                    float* __restrict__ el, float* __restrict__ er,
                    int M, int Nout, int K, int kLen)
{
  constexpr int BM = 128, BK = 32, CF = BN / 16;
  constexpr int BCALLS = (BN * BK) / 512;          // 8 for BN=128, 2 for BN=32
  __shared__ __align__(16) u16 As[BM * BK];
  __shared__ __align__(16) u16 Bs[BN * BK];
  const int tid  = threadIdx.x;
  const int wave = tid >> 6;
  const int lane = tid & 63;
  const int quad = lane >> 4;
  const int l16  = lane & 15;
  const int rowBase = blockIdx.y * BM;
  const int colBase = (OUTM == 2) ? 0 : blockIdx.x * BN;
  const int kStart  = (OUTM == 2) ? blockIdx.x * kLen : 0;

  floatx4 acc[2][CF];
  #pragma unroll
  for (int r = 0; r < 2; ++r)
    #pragma unroll
    for (int c = 0; c < CF; ++c)
      acc[r][c] = (floatx4){0.f, 0.f, 0.f, 0.f};

  // A staging: 8 wave-calls; wave w does calls {w, w+4}.
  int aRow[2], aCol[2];
  #pragma unroll
  for (int i = 0; i < 2; ++i) {
    int call = wave + 4 * i;
    int flat = call * 512 + lane * 8;              // elem idx in 128x32 tile
    int r = flat >> 5;
    aCol[i] = flat & 31;
    int gr = rowBase + r;
    if (gr >= M) gr = M - 1;                       // clamp: safe load, store guarded
    aRow[i] = gr;
  }
  // B staging: BCALLS wave-calls; wave w does {w, w+4} below BCALLS.
  int bRow[2] = {0, 0}, bCol[2] = {0, 0};
  #pragma unroll
  for (int i = 0; i < 2; ++i) {
    int call = wave + 4 * i;
    if (call < BCALLS) {
      int flat = call * 512 + lane * 8;
      bRow[i] = colBase + (flat >> 5);
      bCol[i] = flat & 31;
    }
  }

  for (int k0 = kStart; k0 < kStart + kLen; k0 += BK) {
    __syncthreads();
    #pragma unroll
    for (int i = 0; i < 2; ++i) {
      int call = wave + 4 * i;
      const u16* gp = A + (size_t)aRow[i] * K + (k0 + aCol[i]);
      __builtin_amdgcn_global_load_lds((gas_ptr)gp,
          (las_ptr)(As + call * 512), 16, 0, 0);
    }
    #pragma unroll
    for (int i = 0; i < 2; ++i) {
      int call = wave + 4 * i;
      if (call < BCALLS) {
        const u16* gp = B + (size_t)bRow[i] * K + (k0 + bCol[i]);
        __builtin_amdgcn_global_load_lds((gas_ptr)gp,
            (las_ptr)(Bs + call * 512), 16, 0, 0);
      }
    }
    __syncthreads();
    short8 a0 = *(const short8*)(As + (32 * wave + l16) * BK + quad * 8);
    short8 a1 = *(const short8*)(As + (32 * wave + 16 + l16) * BK + quad * 8);
    #pragma unroll
    for (int c = 0; c < CF; ++c) {
      short8 b = *(const short8*)(Bs + (16 * c + l16) * BK + quad * 8);
      acc[0][c] = __builtin_amdgcn_mfma_f32_16x16x32_bf16(a0, b, acc[0][c], 0, 0, 0);
      acc[1][c] = __builtin_amdgcn_mfma_f32_16x16x32_bf16(a1, b, acc[1][c], 0, 0, 0);
    }
  }

  // C/D layout: col = lane&15, row = quad*4 + reg (verified m89/m91)
  #pragma unroll
  for (int rt = 0; rt < 2; ++rt)
    #pragma unroll
    for (int c = 0; c < CF; ++c)
      #pragma unroll
      for (int i = 0; i < 4; ++i) {
        int gr = rowBase + 32 * wave + 16 * rt + quad * 4 + i;
        if (gr < M) {
          int gc = colBase + 16 * c + l16;
          if (OUTM == 1) Cb[(size_t)gr * Nout + gc] = f2bf(acc[rt][c][i]);
          else           atomicAdd(Cf + (size_t)gr * Nout + gc, acc[rt][c][i]);
        }
      }

  // ---- fused el/er epilogue (from f32 acc: closer to reference than bf16 z) ----
  if (OUTM == 1) {
    // BN=128 -> this block covers heads {colBase/64, colBase/64+1} entirely.
    #pragma unroll
    for (int rt = 0; rt < 2; ++rt)
      #pragma unroll
      for (int i = 0; i < 4; ++i) {
        int gr = rowBase + 32 * wave + 16 * rt + quad * 4 + i;
        #pragma unroll
        for (int hp = 0; hp < 2; ++hp) {
          float sl = 0.f, sr = 0.f;
          #pragma unroll
          for (int cc = 0; cc < 4; ++cc) {
            int c = hp * 4 + cc;
            int gc = colBase + 16 * c + l16;
            float zv = acc[rt][c][i];
            sl += zv * al[gc];
            sr += zv * ar[gc];
          }
          #pragma unroll
          for (int m = 1; m < 16; m <<= 1) {     // reduce over l16 (lane bits 0..3)
            sl += __shfl_xor(sl, m, 64);
            sr += __shfl_xor(sr, m, 64);
          }
          if (l16 == 0 && gr < M) {
            int hh = colBase / 64 + hp;
            el[(size_t)gr * 8 + hh] = sl;        // exactly one block owns (gr,hh)
            er[(size_t)gr * 8 + hh] = sr;
          }
        }
      }
  } else {
    // BN=32, H=1: partial el/er per split-K chunk, atomicAdd (linear in partials).
    #pragma unroll
    for (int rt = 0; rt < 2; ++rt)
      #pragma unroll
      for (int i = 0; i < 4; ++i) {
        int gr = rowBase + 32 * wave + 16 * rt + quad * 4 + i;
        float sl = 0.f, sr = 0.f;
        #pragma unroll
        for (int c = 0; c < CF; ++c) {
          int gc = 16 * c + l16;
          float zv = acc[rt][c][i];
          sl += zv * al[gc];
          sr += zv * ar[gc];
        }
        #pragma unroll
        for (int m = 1; m < 16; m <<= 1) {
          sl += __shfl_xor(sl, m, 64);
          sr += __shfl_xor(sr, m, 64);
        }
        if (l16 == 0 && gr < M) {
          atomicAdd(el + gr, sl);
          atomicAdd(er + gr, sr);
        }
      }
  }
}

// ---------- layers 1/2 aggregate: bf16 z gather, 1 wave/node, 8 cols/thread ----------
// out = sum_e exp(v_e) z[src_e] / sum_e exp(v_e)  (shift-invariant softmax, no max pass)
// Epilogue writes next layer's A' = [hi|lo] (row len 1024).
// NOTE (r1 post-mortem): gather is BW-ceiling-bound (~3.6 TB/s for random 1KB rows,
// L2-miss traffic ~= 8 XCDs x 25.6MB); schedule changes don't move it. Keep the
// low-VGPR guarded form (r0: 67.5us vs branchless 69.3us).
__global__ __launch_bounds__(64)
void agg_bf16_kernel(const u16* __restrict__ z, const float* __restrict__ el,
                     const float* __restrict__ er, const int* __restrict__ src,
                     const int* __restrict__ rs, u16* __restrict__ a2out)
{
  const int n = blockIdx.x, tid = threadIdx.x;
  const int s = rs[n], e = rs[n + 1];
  const int c0 = tid * 8;                          // 8 bf16 cols = 16 B/lane
  const int h = tid >> 3;                          // c0 / 64
  const float er_h = er[(size_t)n * 8 + h];

  float acc[8];
  #pragma unroll
  for (int j = 0; j < 8; ++j) acc[j] = 0.f;
  float den = 0.f;

  for (int k0 = s; k0 < e; k0 += 8) {
    const int kc = e - k0;
    #pragma unroll
    for (int kk = 0; kk < 8; ++kk) {
      if (kk < kc) {                               // wave-uniform guard
        int si = src[k0 + kk];                     // broadcast load
        float v = el[(size_t)si * 8 + h] + er_h;   // broadcast load
        v = (v > 0.f) ? v : 0.2f * v;              // leaky_relu 0.2
        float wgt = __expf(v);
        u32x4 zz = *(const u32x4*)(z + (size_t)si * 512 + c0);  // 16B/lane coalesced
        #pragma unroll
        for (int j = 0; j < 4; ++j) {
          acc[2 * j]     += wgt * bf_lo(zz[j]);
          acc[2 * j + 1] += wgt * bf_hi(zz[j]);
        }
        den += wgt;
      }
    }
  }

  const float r = (e > s) ? (1.f / den) : 0.f;     // deg==0 -> zeros (elu(0)=0)
  u32x4 hp, lp;
  #pragma unroll
  for (int j = 0; j < 4; ++j) {
    float o0 = acc[2 * j] * r, o1 = acc[2 * j + 1] * r;
    o0 = (o0 > 0.f) ? o0 : (__expf(o0) - 1.f);     // elu
    o1 = (o1 > 0.f) ? o1 : (__expf(o1) - 1.f);
    u16 h0 = f2bf(o0), h1 = f2bf(o1);
    u16 l0 = f2bf(o0 - bf2f(h0)), l1 = f2bf(o1 - bf2f(h1));
    hp[j] = ((u32)h1 << 16) | h0;
    lp[j] = ((u32)l1 << 16) | l0;
  }
  u16* row = a2out + (size_t)n * 1024;             // A' = [hi|lo]
  *(u32x4*)(row + c0) = hp;
  *(u32x4*)(row + 512 + c0) = lp;
}

// ---------- layer 3 aggregate: f32 z3 (3.2 MB, L2-resident), 32 cols ----------
__global__ __launch_bounds__(64)
void agg3_kernel(const float* __restrict__ z, const float* __restrict__ el,
                 const float* __restrict__ er, const int* __restrict__ src,
                 const int* __restrict__ rs, float* __restrict__ out)
{
  const int n = blockIdx.x, tid = threadIdx.x;
  const int s = rs[n], e = rs[n + 1];
  const bool active = (tid < 32);
  const float er_n = er[n];
  float acc = 0.f, den = 0.f;

  for (int k0 = s; k0 < e; k0 += 8) {
    const int kc = e - k0;
    #pragma unroll
    for (int kk = 0; kk < 8; ++kk) {
      if (kk < kc) {
        int si = src[k0 + kk];
        float v = el[si] + er_n;
        v = (v > 0.f) ? v : 0.2f * v;
        float wgt = __expf(v);
        if (active) acc += wgt * z[(size_t)si * 32 + tid];
        den += wgt;
      }
    }
  }
  if (active) out[(size_t)n * 32 + tid] = (e > s) ? (acc / den) : 0.f;
}

extern "C" void kernel_launch(void* const* d_in, const int* in_sizes, int n_in,
                              void* d_out, int out_size, void* d_ws, size_t ws_size,
                              hipStream_t stream)
{
  constexpr int N = 25000, E = 400000, K1 = 256, HF = 512, CLS = 32;
  const float* h   = (const float*)d_in[0];
  const int*   src = (const int*)d_in[1];
  const int*   dst = (const int*)d_in[2];
  const float* W1  = (const float*)d_in[3];
  const float* al1 = (const float*)d_in[4];
  const float* ar1 = (const float*)d_in[5];
  const float* W2  = (const float*)d_in[6];
  const float* al2 = (const float*)d_in[7];
  const float* ar2 = (const float*)d_in[8];
  const float* W3  = (const float*)d_in[9];
  const float* al3 = (const float*)d_in[10];
  const float* ar3 = (const float*)d_in[11];
  float* out = (float*)d_out;

  char* w = (char*)d_ws;
  auto take = [&](size_t bytes) {
    char* p = w;
    w += (bytes + 255) & ~(size_t)255;
    return p;
  };
  int*   rs = (int*)  take((size_t)(N + 1) * sizeof(int));
  float* el = (float*)take((size_t)N * 8 * sizeof(float));
  float* er = (float*)take((size_t)N * 8 * sizeof(float));
  float* z3 = (float*)take((size_t)N * CLS * sizeof(float));         // 3.2 MB
  u16*   zb = (u16*)  take((size_t)N * HF * sizeof(u16));            // 25.6 MB
  u16*   A2 = (u16*)  take((size_t)N * 2 * HF * sizeof(u16));        // 51.2 MB
  u16*   B1 = (u16*)  take((size_t)HF * 2 * K1 * sizeof(u16));       // 0.5 MB
  u16*   B2 = (u16*)  take((size_t)HF * 2 * HF * sizeof(u16));       // 1.05 MB
  u16*   B3 = (u16*)  take((size_t)CLS * 2 * HF * sizeof(u16));      // 64 KB

  // ---- independent prep, hoisted to the front ----
  rowstart_kernel<<<dim3((N + 1 + 255) / 256), 256, 0, stream>>>(dst, rs, N, E);
  split_kernel<true ><<<dim3((N * K1 + 255) / 256), 256, 0, stream>>>(h,  A2, N * K1, K1);
  split_kernel<false><<<dim3((HF * K1 + 255) / 256), 256, 0, stream>>>(W1, B1, HF * K1, K1);
  split_kernel<false><<<dim3((HF * HF + 255) / 256), 256, 0, stream>>>(W2, B2, HF * HF, HF);
  split_kernel<false><<<dim3((CLS * HF + 255) / 256), 256, 0, stream>>>(W3, B3, CLS * HF, HF);

  const dim3 gemmGrid(HF / 128, (N + 127) / 128);   // 4 x 196

  // ---- Layer 1: K'=512, elr fused into GEMM epilogue ----
  gemm_bt_kernel<128, 1><<<gemmGrid, 256, 0, stream>>>(A2, B1, nullptr, zb,
      al1, ar1, el, er, N, HF, 2 * K1, 2 * K1);
  agg_bf16_kernel<<<dim3(N), 64, 0, stream>>>(zb, el, er, src, rs, A2);

  // ---- Layer 2: K'=1024, elr fused ----
  gemm_bt_kernel<128, 1><<<gemmGrid, 256, 0, stream>>>(A2, B2, nullptr, zb,
      al2, ar2, el, er, N, HF, 2 * HF, 2 * HF);
  agg_bf16_kernel<<<dim3(N), 64, 0, stream>>>(zb, el, er, src, rs, A2);

  // ---- Layer 3: K'=1024, Nout=32, split-K=4 + atomicAdd, elr fused (atomic) ----
  zero3_kernel<<<dim3((N * CLS + 2 * N + 255) / 256), 256, 0, stream>>>(z3, el, er, N * CLS, N);
  gemm_bt_kernel<32, 2><<<dim3(4, (N + 127) / 128), 256, 0, stream>>>(A2, B3, z3, nullptr,
      al3, ar3, el, er, N, CLS, 2 * HF, (2 * HF) / 4);
  agg3_kernel<<<dim3(N), 64, 0, stream>>>(z3, el, er, src, rs, out);
}

// Round 4
// 384.928 us; speedup vs baseline: 1.1099x; 1.0466x over previous
//
#include <hip/hip_runtime.h>
#include <cstdint>

#define DEVINL __device__ __forceinline__

typedef uint16_t u16;
typedef uint32_t u32;
typedef uint64_t u64;
typedef __attribute__((ext_vector_type(8))) short short8;
typedef __attribute__((ext_vector_type(4))) float floatx4;
typedef __attribute__((ext_vector_type(4))) u32 u32x4;
typedef const __attribute__((address_space(1))) void* gas_ptr;
typedef __attribute__((address_space(3))) void* las_ptr;

DEVINL u16 f2bf(float f) {
  u32 u = __float_as_uint(f);
  u32 r = u + 0x7FFFu + ((u >> 16) & 1u);   // RNE
  return (u16)(r >> 16);
}
DEVINL float bf2f(u16 b) { return __uint_as_float((u32)b << 16); }
DEVINL float bf_lo(u32 u) { return __uint_as_float(u << 16); }
DEVINL float bf_hi(u32 u) { return __uint_as_float(u & 0xFFFF0000u); }

// Operand layout for GEMM: K-chunked tiles  T[ck][row][64], ck = k/64.
// A' rows padded to Mpad=25088 so block row-tiles read contiguous 16KB with no clamp
// (garbage rows feed MFMA but their outputs are store-guarded).

// ---------- row_start[n] = lower_bound(dst, n) over sorted dst ----------
__global__ void rowstart_kernel(const int* __restrict__ dst, int* __restrict__ rs,
                                int N, int E) {
  int n = blockIdx.x * blockDim.x + threadIdx.x;
  if (n > N) return;
  int lo = 0, hi = E;
  while (lo < hi) { int mid = (lo + hi) >> 1; if (dst[mid] < n) lo = mid + 1; else hi = mid; }
  rs[n] = lo;
}

// zero z3 + el + er in one launch (layer-3 atomic targets)
__global__ void zero3_kernel(float* __restrict__ z3, float* __restrict__ el,
                             float* __restrict__ er, int nz, int ne) {
  int i = blockIdx.x * blockDim.x + threadIdx.x;
  if (i < nz) { z3[i] = 0.f; return; }
  int j = i - nz;
  if (j < ne) { el[j] = 0.f; return; }
  j -= ne;
  if (j < ne) er[j] = 0.f;
}

// ---------- h (f32 [N][256]) -> A1 tiled [8][Mpad][64], exact hi/lo split ----------
__global__ __launch_bounds__(256)
void splitA_kernel(const float* __restrict__ in, u16* __restrict__ out,
                   int M, int Mpad) {
  int idx = blockIdx.x * blockDim.x + threadIdx.x;
  if (idx >= M * 256) return;
  int m = idx >> 8, k = idx & 255;
  float a = in[idx];
  u16 h = f2bf(a);
  u16 lo = f2bf(a - bf2f(h));
  size_t cs = (size_t)Mpad * 64;
  size_t pos = (size_t)m * 64 + (k & 63);
  out[(size_t)(k >> 6) * cs + pos] = h;          // hi chunks 0..3
  out[(size_t)((k >> 6) + 4) * cs + pos] = lo;   // lo chunks 4..7
}

// ---------- W1/W2/W3 -> B1/B2/B3 tiled (bf16 hi duplicated), one launch ----------
__global__ __launch_bounds__(256)
void splitW_kernel(const float* __restrict__ W1, const float* __restrict__ W2,
                   const float* __restrict__ W3, u16* __restrict__ B1,
                   u16* __restrict__ B2, u16* __restrict__ B3) {
  int idx = blockIdx.x * blockDim.x + threadIdx.x;
  if (idx < 512 * 256) {                          // W1 [512][256] -> [8][512][64]
    int m = idx >> 8, k = idx & 255;
    u16 h = f2bf(W1[idx]);
    size_t cs = 512 * 64;
    size_t pos = (size_t)m * 64 + (k & 63);
    B1[(size_t)(k >> 6) * cs + pos] = h;
    B1[(size_t)((k >> 6) + 4) * cs + pos] = h;
    return;
  }
  idx -= 512 * 256;
  if (idx < 512 * 512) {                          // W2 [512][512] -> [16][512][64]
    int m = idx >> 9, k = idx & 511;
    u16 h = f2bf(W2[idx]);
    size_t cs = 512 * 64;
    size_t pos = (size_t)m * 64 + (k & 63);
    B2[(size_t)(k >> 6) * cs + pos] = h;
    B2[(size_t)((k >> 6) + 8) * cs + pos] = h;
    return;
  }
  idx -= 512 * 512;
  if (idx < 32 * 512) {                           // W3 [32][512] -> [16][32][64]
    int m = idx >> 9, k = idx & 511;
    u16 h = f2bf(W3[idx]);
    size_t cs = 32 * 64;
    size_t pos = (size_t)m * 64 + (k & 63);
    B3[(size_t)(k >> 6) * cs + pos] = h;
    B3[(size_t)((k >> 6) + 8) * cs + pos] = h;
  }
}

// ---------- GEMM: C[M,Nout] = A'[M,K'] * B'[Nout,K']^T, K-chunked operands ----------
// BM=128, BK=64 (one chunk/step), 256 threads (4 waves); wave w owns rows [32w,32w+32).
// Staging: one global_load_lds call = 64 lanes x 16B = 512 u16 = 8 tile-rows.
//   A tile = 128x64 u16 = 16 calls (4/wave). B tile = BNx64 = BN/8 calls.
//   (R3 BUG: 8/wave = 32 calls overflowed As into Bs -> LDS race, absmax fail.)
// LDS XOR-swizzle (granule ^= row&7): pre-swizzled GLOBAL source + swizzled ds_read,
// linear global_load_lds dest (rule: both-sides-or-neither). Conflict-free b128 reads.
// OUTM 1: bf16 C store + el/er store epilogue; XCD-grouped bid decode (the 4 column
//         blocks of one row-tile land on one XCD -> A-tile fetched once per L2).
// OUTM 2: split-K f32 atomicAdd + el/er atomicAdd epilogue.
template<int BN, int OUTM>
__global__ __launch_bounds__(256)
void gemm_bt_kernel(const u16* __restrict__ A, const u16* __restrict__ B,
                    float* __restrict__ Cf, u16* __restrict__ Cb,
                    const float* __restrict__ al, const float* __restrict__ ar,
                    float* __restrict__ el, float* __restrict__ er,
                    int M, int Nout, int Mpad, int kcLen)
{
  constexpr int BM = 128, CF = BN / 16;
  constexpr int BCALLS_B = (BN * 64) / 512;       // 16 for BN=128, 4 for BN=32
  __shared__ __align__(16) u16 As[BM * 64];       // 16 KB
  __shared__ __align__(16) u16 Bs[BN * 64];
  const int tid  = threadIdx.x;
  const int wave = tid >> 6;
  const int lane = tid & 63;
  const int quad = lane >> 4;
  const int l16  = lane & 15;
  const int lrow = lane >> 3;                     // sub-row within a 512-elem call
  const int lq   = lane & 7;                      // 16B-granule within row

  int bx, by;
  if (OUTM == 1) {
    // XCD grouping: bid = y%8 + 8*x + 32*(y/8) for full groups of 8 y's.
    int bid = blockIdx.x;
    int nY = (M + 127) >> 7;
    int fullG = nY >> 3;
    if ((bid >> 5) < fullG) {
      int rem = bid & 31;
      by = ((bid >> 5) << 3) + (rem & 7);
      bx = rem >> 3;
    } else {
      int t = bid - (fullG << 5);
      int tailY = nY - (fullG << 3);
      by = (fullG << 3) + t % tailY;
      bx = t / tailY;
    }
  } else { bx = blockIdx.x; by = blockIdx.y; }

  const int rowBase = by * BM;
  const int colBase = (OUTM == 2) ? 0 : bx * BN;
  const int kcStart = (OUTM == 2) ? bx * kcLen : 0;

  floatx4 acc[2][CF];
  #pragma unroll
  for (int r = 0; r < 2; ++r)
    #pragma unroll
    for (int c = 0; c < CF; ++c)
      acc[r][c] = (floatx4){0.f, 0.f, 0.f, 0.f};

  const size_t aCS = (size_t)Mpad * 64;
  const size_t bCS = (size_t)Nout * 64;
  const u16* aTile = A + (size_t)rowBase * 64;
  const u16* bTile = B + (size_t)colBase * 64;

  for (int kc = kcStart; kc < kcStart + kcLen; ++kc) {
    __syncthreads();
    const u16* aB = aTile + (size_t)kc * aCS;
    #pragma unroll
    for (int i = 0; i < 4; ++i) {                 // A: 16 calls, 4/wave (16KB tile)
      int c = wave * 4 + i;
      int row = c * 8 + lrow;
      const u16* gp = aB + row * 64 + (((lq ^ (row & 7))) << 3);
      __builtin_amdgcn_global_load_lds((gas_ptr)gp, (las_ptr)(As + c * 512), 16, 0, 0);
    }
    const u16* bB = bTile + (size_t)kc * bCS;
    #pragma unroll
    for (int i = 0; i < BCALLS_B / 4; ++i) {      // B: BCALLS_B calls
      int c = wave * (BCALLS_B / 4) + i;
      int row = c * 8 + lrow;
      const u16* gp = bB + row * 64 + (((lq ^ (row & 7))) << 3);
      __builtin_amdgcn_global_load_lds((gas_ptr)gp, (las_ptr)(Bs + c * 512), 16, 0, 0);
    }
    __syncthreads();
    #pragma unroll
    for (int kk = 0; kk < 2; ++kk) {              // 32 MFMA per barrier drain
      const int r0 = 32 * wave + l16;
      const int r1 = r0 + 16;
      short8 a0 = *(const short8*)(As + r0 * 64 + ((((kk << 2) + quad) ^ (r0 & 7)) << 3));
      short8 a1 = *(const short8*)(As + r1 * 64 + ((((kk << 2) + quad) ^ (r1 & 7)) << 3));
      #pragma unroll
      for (int c = 0; c < CF; ++c) {
        int rb = 16 * c + l16;
        short8 b = *(const short8*)(Bs + rb * 64 + ((((kk << 2) + quad) ^ (rb & 7)) << 3));
        acc[0][c] = __builtin_amdgcn_mfma_f32_16x16x32_bf16(a0, b, acc[0][c], 0, 0, 0);
        acc[1][c] = __builtin_amdgcn_mfma_f32_16x16x32_bf16(a1, b, acc[1][c], 0, 0, 0);
      }
    }
  }

  // C/D layout: col = lane&15, row = quad*4 + reg (verified m89/m91)
  #pragma unroll
  for (int rt = 0; rt < 2; ++rt)
    #pragma unroll
    for (int c = 0; c < CF; ++c)
      #pragma unroll
      for (int i = 0; i < 4; ++i) {
        int gr = rowBase + 32 * wave + 16 * rt + quad * 4 + i;
        if (gr < M) {
          int gc = colBase + 16 * c + l16;
          if (OUTM == 1) Cb[(size_t)gr * Nout + gc] = f2bf(acc[rt][c][i]);
          else           atomicAdd(Cf + (size_t)gr * Nout + gc, acc[rt][c][i]);
        }
      }

  // ---- fused el/er epilogue (from f32 acc) ----
  if (OUTM == 1) {
    #pragma unroll
    for (int rt = 0; rt < 2; ++rt)
      #pragma unroll
      for (int i = 0; i < 4; ++i) {
        int gr = rowBase + 32 * wave + 16 * rt + quad * 4 + i;
        #pragma unroll
        for (int hp = 0; hp < 2; ++hp) {
          float sl = 0.f, sr = 0.f;
          #pragma unroll
          for (int cc = 0; cc < 4; ++cc) {
            int c = hp * 4 + cc;
            int gc = colBase + 16 * c + l16;
            float zv = acc[rt][c][i];
            sl += zv * al[gc];
            sr += zv * ar[gc];
          }
          #pragma unroll
          for (int m = 1; m < 16; m <<= 1) {
            sl += __shfl_xor(sl, m, 64);
            sr += __shfl_xor(sr, m, 64);
          }
          if (l16 == 0 && gr < M) {
            int hh = colBase / 64 + hp;
            el[(size_t)gr * 8 + hh] = sl;
            er[(size_t)gr * 8 + hh] = sr;
          }
        }
      }
  } else {
    #pragma unroll
    for (int rt = 0; rt < 2; ++rt)
      #pragma unroll
      for (int i = 0; i < 4; ++i) {
        int gr = rowBase + 32 * wave + 16 * rt + quad * 4 + i;
        float sl = 0.f, sr = 0.f;
        #pragma unroll
        for (int c = 0; c < CF; ++c) {
          int gc = 16 * c + l16;
          float zv = acc[rt][c][i];
          sl += zv * al[gc];
          sr += zv * ar[gc];
        }
        #pragma unroll
        for (int m = 1; m < 16; m <<= 1) {
          sl += __shfl_xor(sl, m, 64);
          sr += __shfl_xor(sr, m, 64);
        }
        if (l16 == 0 && gr < M) {
          atomicAdd(el + gr, sl);
          atomicAdd(er + gr, sr);
        }
      }
  }
}

// ---------- layers 1/2 aggregate: bf16 z gather, 1 wave/node, 8 cols/thread ----------
// out = sum_e exp(v_e) z[src_e] / sum_e exp(v_e)  (shift-invariant softmax, no max pass)
// Epilogue writes next layer's A' K-chunked: [16][Mpad][64] (hi ck 0..7, lo 8..15).
// NOTE (r1 post-mortem): gather is BW-ceiling-bound (~3.6 TB/s for random 1KB rows);
// schedule changes don't move it. Keep the low-VGPR guarded form.
__global__ __launch_bounds__(64)
void agg_bf16_kernel(const u16* __restrict__ z, const float* __restrict__ el,
                     const float* __restrict__ er, const int* __restrict__ src,
                     const int* __restrict__ rs, u16* __restrict__ a2out, int Mpad)
{
  const int n = blockIdx.x, tid = threadIdx.x;
  const int s = rs[n], e = rs[n + 1];
  const int c0 = tid * 8;                          // 8 bf16 cols = 16 B/lane
  const int h = tid >> 3;                          // c0 / 64
  const float er_h = er[(size_t)n * 8 + h];

  float acc[8];
  #pragma unroll
  for (int j = 0; j < 8; ++j) acc[j] = 0.f;
  float den = 0.f;

  for (int k0 = s; k0 < e; k0 += 8) {
    const int kc = e - k0;
    #pragma unroll
    for (int kk = 0; kk < 8; ++kk) {
      if (kk < kc) {                               // wave-uniform guard
        int si = src[k0 + kk];                     // broadcast load
        float v = el[(size_t)si * 8 + h] + er_h;   // broadcast load
        v = (v > 0.f) ? v : 0.2f * v;              // leaky_relu 0.2
        float wgt = __expf(v);
        u32x4 zz = *(const u32x4*)(z + (size_t)si * 512 + c0);  // 16B/lane coalesced
        #pragma unroll
        for (int j = 0; j < 4; ++j) {
          acc[2 * j]     += wgt * bf_lo(zz[j]);
          acc[2 * j + 1] += wgt * bf_hi(zz[j]);
        }
        den += wgt;
      }
    }
  }

  const float r = (e > s) ? (1.f / den) : 0.f;     // deg==0 -> zeros (elu(0)=0)
  u32x4 hp, lp;
  #pragma unroll
  for (int j = 0; j < 4; ++j) {
    float o0 = acc[2 * j] * r, o1 = acc[2 * j + 1] * r;
    o0 = (o0 > 0.f) ? o0 : (__expf(o0) - 1.f);     // elu
    o1 = (o1 > 0.f) ? o1 : (__expf(o1) - 1.f);
    u16 h0 = f2bf(o0), h1 = f2bf(o1);
    u16 l0 = f2bf(o0 - bf2f(h0)), l1 = f2bf(o1 - bf2f(h1));
    hp[j] = ((u32)h1 << 16) | h0;
    lp[j] = ((u32)l1 << 16) | l0;
  }
  // tiled A' store: chunk = c0/64, offset = c0%64 (8 lanes -> 128B contiguous runs)
  const int ck = tid >> 3;
  const int ko = (tid & 7) << 3;
  const size_t cs = (size_t)Mpad * 64;
  u16* p = a2out + (size_t)n * 64 + ko;
  *(u32x4*)(p + (size_t)ck * cs) = hp;
  *(u32x4*)(p + (size_t)(ck + 8) * cs) = lp;
}

// ---------- layer 3 aggregate: f32 z3 (3.2 MB, L2-resident), 32 cols ----------
__global__ __launch_bounds__(64)
void agg3_kernel(const float* __restrict__ z, const float* __restrict__ el,
                 const float* __restrict__ er, const int* __restrict__ src,
                 const int* __restrict__ rs, float* __restrict__ out)
{
  const int n = blockIdx.x, tid = threadIdx.x;
  const int s = rs[n], e = rs[n + 1];
  const bool active = (tid < 32);
  const float er_n = er[n];
  float acc = 0.f, den = 0.f;

  for (int k0 = s; k0 < e; k0 += 8) {
    const int kc = e - k0;
    #pragma unroll
    for (int kk = 0; kk < 8; ++kk) {
      if (kk < kc) {
        int si = src[k0 + kk];
        float v = el[si] + er_n;
        v = (v > 0.f) ? v : 0.2f * v;
        float wgt = __expf(v);
        if (active) acc += wgt * z[(size_t)si * 32 + tid];
        den += wgt;
      }
    }
  }
  if (active) out[(size_t)n * 32 + tid] = (e > s) ? (acc / den) : 0.f;
}

extern "C" void kernel_launch(void* const* d_in, const int* in_sizes, int n_in,
                              void* d_out, int out_size, void* d_ws, size_t ws_size,
                              hipStream_t stream)
{
  constexpr int N = 25000, E = 400000, K1 = 256, HF = 512, CLS = 32;
  constexpr int Mpad = 25088;                       // 196 * 128
  const float* h   = (const float*)d_in[0];
  const int*   src = (const int*)d_in[1];
  const int*   dst = (const int*)d_in[2];
  const float* W1  = (const float*)d_in[3];
  const float* al1 = (const float*)d_in[4];
  const float* ar1 = (const float*)d_in[5];
  const float* W2  = (const float*)d_in[6];
  const float* al2 = (const float*)d_in[7];
  const float* ar2 = (const float*)d_in[8];
  const float* W3  = (const float*)d_in[9];
  const float* al3 = (const float*)d_in[10];
  const float* ar3 = (const float*)d_in[11];
  float* out = (float*)d_out;

  char* w = (char*)d_ws;
  auto take = [&](size_t bytes) {
    char* p = w;
    w += (bytes + 255) & ~(size_t)255;
    return p;
  };
  int*   rs = (int*)  take((size_t)(N + 1) * sizeof(int));
  float* el = (float*)take((size_t)N * 8 * sizeof(float));
  float* er = (float*)take((size_t)N * 8 * sizeof(float));
  float* z3 = (float*)take((size_t)N * CLS * sizeof(float));          // 3.2 MB
  u16*   zb = (u16*)  take((size_t)N * HF * sizeof(u16));             // 25.6 MB
  u16*   A2 = (u16*)  take((size_t)16 * Mpad * 64 * sizeof(u16));     // 51.4 MB
  u16*   B1 = (u16*)  take((size_t)8  * HF * 64 * sizeof(u16));       // 0.52 MB
  u16*   B2 = (u16*)  take((size_t)16 * HF * 64 * sizeof(u16));       // 1.05 MB
  u16*   B3 = (u16*)  take((size_t)16 * CLS * 64 * sizeof(u16));      // 64 KB
  u16*   A1 = A2;       // layer-1 A (8 chunks) aliases A2; dead before agg1 writes

  // ---- independent prep ----
  rowstart_kernel<<<dim3((N + 1 + 255) / 256), 256, 0, stream>>>(dst, rs, N, E);
  splitA_kernel<<<dim3((N * K1) / 256), 256, 0, stream>>>(h, A1, N, Mpad);
  splitW_kernel<<<dim3(1600), 256, 0, stream>>>(W1, W2, W3, B1, B2, B3);

  const int gemmBlocks = 4 * (Mpad / 128);          // 784, 1-D XCD-grouped decode

  // ---- Layer 1: K'=512 (8 chunks), elr fused ----
  gemm_bt_kernel<128, 1><<<dim3(gemmBlocks), 256, 0, stream>>>(A1, B1, nullptr, zb,
      al1, ar1, el, er, N, HF, Mpad, 8);
  agg_bf16_kernel<<<dim3(N), 64, 0, stream>>>(zb, el, er, src, rs, A2, Mpad);

  // ---- Layer 2: K'=1024 (16 chunks), elr fused ----
  gemm_bt_kernel<128, 1><<<dim3(gemmBlocks), 256, 0, stream>>>(A2, B2, nullptr, zb,
      al2, ar2, el, er, N, HF, Mpad, 16);
  agg_bf16_kernel<<<dim3(N), 64, 0, stream>>>(zb, el, er, src, rs, A2, Mpad);

  // ---- Layer 3: split-K=4 (4 chunks each) + atomicAdd, elr fused (atomic) ----
  zero3_kernel<<<dim3((N * CLS + 2 * N + 255) / 256), 256, 0, stream>>>(z3, el, er, N * CLS, N);
  gemm_bt_kernel<32, 2><<<dim3(4, Mpad / 128), 256, 0, stream>>>(A2, B3, z3, nullptr,
      al3, ar3, el, er, N, CLS, Mpad, 4);
  agg3_kernel<<<dim3(N), 64, 0, stream>>>(z3, el, er, src, rs, out);
}